// Round 18
// baseline (165.783 us; speedup 1.0000x reference)
//
#include <hip/hip_runtime.h>

// LinearAutoDecoder R18: R17 (coalesced MFMA tiles) + counted-barrier schedule.
// R17's remaining 1.6x over HBM floor: __syncthreads emits
// s_waitcnt vmcnt(0) lgkmcnt(0) before s_barrier, draining the tile t+1
// prefetch at barrier A -- HBM latency serialized with MFMA every tile.
// Fix (T4 / m201 pattern): raw s_barrier + lgkmcnt(0)-only waits; the VMEM
// prefetch stays in flight across the barrier and MFMA phase; the compiler's
// register-dep waitcnt on xr (next staging, ~2000cyc later) is the only drain.

constexpr int POS = 63, LAT = 256, DIM = 319, NCH = 192;
constexpr int ROWS = 32;                    // rows per tile
constexpr int KPAD = 328;                   // bf16 per LDS X row
constexpr int CST  = 196;                   // fp32 per LDS C row
constexpr int PW_DW = NCH * 160;            // 30720 dwords (320 bf16/ch)
constexpr size_t PW_BYTES = (size_t)PW_DW * 4;
constexpr int TILE_F4 = ROWS * DIM / 4;     // 2552 float4 per tile slab
constexpr int TPB = 4;                      // tiles per block

typedef __attribute__((ext_vector_type(8))) short short8;
typedef __attribute__((ext_vector_type(4))) float f32x4;

__device__ __forceinline__ unsigned f2bf(float f) {
    unsigned u = __float_as_uint(f);
    return (u + 0x7fffu + ((u >> 16) & 1u)) >> 16;
}

// DS-only barrier: waves sync without draining outstanding VMEM loads.
__device__ __forceinline__ void ds_barrier() {
    asm volatile("s_waitcnt lgkmcnt(0)" ::: "memory");
    __builtin_amdgcn_s_barrier();
}

// pw[ch*160 + d] = bf16(w[ch][2d]) | bf16(w[ch][2d+1])<<16 ; k=319 -> 0
__global__ __launch_bounds__(256) void pack_weights(
    const float* __restrict__ Wp, const float* __restrict__ Wf,
    unsigned* __restrict__ pw)
{
    const int idx = blockIdx.x * 256 + threadIdx.x;
    if (idx >= PW_DW) return;
    const int ch = idx / 160, d = idx - ch * 160;
    auto wat = [&](int k) -> float {
        if (k < POS) return Wp[ch * POS + k];
        if (k < DIM) return Wf[ch * LAT + (k - POS)];
        return 0.f;
    };
    pw[idx] = f2bf(wat(2 * d)) | (f2bf(wat(2 * d + 1)) << 16);
}

__global__ __launch_bounds__(256, 2) void lad_mfma(
    const float4* __restrict__ X4, const int* __restrict__ cid,
    const unsigned* __restrict__ pw, float* __restrict__ out,
    int ntiles, long nf4)
{
    __shared__ __align__(16) unsigned short xb[ROWS * KPAD];  // 20,992 B
    __shared__ float cbuf[ROWS * CST];                        // 25,088 B

    const int thr = threadIdx.x;
    const int l   = thr & 63;
    const int wid = thr >> 6;
    const int n0  = wid * 48;        // wave's channel base (4 x 48 = 192)
    const int cl  = l & 15;          // row(A) / col(B,C)
    const int q   = l >> 4;          // k-quad

    // B fragments: 48 channels x K=320 in VGPRs, loaded once per block.
    short8 Bf[3][10];
#pragma unroll
    for (int nt = 0; nt < 3; ++nt)
#pragma unroll
        for (int kk = 0; kk < 10; ++kk) {
            const unsigned* p = pw + (size_t)(n0 + nt * 16 + cl) * 160
                                   + kk * 16 + q * 4;
            Bf[nt][kk] = *reinterpret_cast<const short8*>(p);
        }

    if (thr < ROWS) xb[thr * KPAD + 319] = 0;   // zero pad col (persists)

    const int t0 = blockIdx.x * TPB;
    const int tend = min(t0 + TPB, ntiles);
    if (t0 >= tend) return;

    // Prologue: load tile t0's slab (coalesced, iteration-major).
    float4 xr[10];
    {
        const long b4 = (long)t0 * TILE_F4;
#pragma unroll
        for (int i = 0; i < 10; ++i) {
            long idx = b4 + i * 256 + thr;
            if (idx >= nf4) idx = nf4 - 1;
            xr[i] = X4[idx];
        }
    }

    for (int t = t0; t < tend; ++t) {
        // Gather previous tile's outputs (cbuf valid since barrier B).
        if (t > t0 && thr < 96) {
            const int r = thr / 3, j = thr - r * 3;
            const int c = cid[(size_t)(t - 1) * ROWS + r];
            out[((size_t)(t - 1) * ROWS + r) * 3 + j] = cbuf[r * CST + 3 * c + j];
        }

        // Stage tile t: fp32 regs -> bf16 LDS (consumes xr).
        {
#pragma unroll
            for (int i = 0; i < 10; ++i) {
                const int s = i * 256 + thr;          // slot id
                const float4 v = xr[i];
#pragma unroll
                for (int e = 0; e < 4; ++e) {
                    const int p = 4 * s + e;
                    const float f = (e == 0) ? v.x : (e == 1) ? v.y
                                  : (e == 2) ? v.z : v.w;
                    const int r = (int)((unsigned)p / 319u);
                    if (r < ROWS) {
                        const int k = p - r * 319;
                        xb[r * KPAD + k] = (unsigned short)f2bf(f);
                    }
                }
            }
        }

        // Prefetch tile t+1's slab: ISSUED here, stays in flight across the
        // barrier (lgkmcnt-only) and the whole MFMA phase.
        if (t + 1 < tend) {
            const long b4 = (long)(t + 1) * TILE_F4;
#pragma unroll
            for (int i = 0; i < 10; ++i) {
                long idx = b4 + i * 256 + thr;
                if (idx >= nf4) idx = nf4 - 1;
                xr[i] = X4[idx];
            }
        }

        ds_barrier();   // barrier A: xb(t) staged, gather(t-1) done. No vmcnt drain.

        // MFMA: this wave computes C[32 x 48] over K=320.
        f32x4 acc[2][3];
#pragma unroll
        for (int mt = 0; mt < 2; ++mt)
#pragma unroll
            for (int nt = 0; nt < 3; ++nt)
                acc[mt][nt] = (f32x4)0.0f;

#pragma unroll
        for (int kk = 0; kk < 10; ++kk) {
            short8 Af[2];
#pragma unroll
            for (int mt = 0; mt < 2; ++mt) {
                const int row = mt * 16 + cl;
                const int k   = kk * 32 + q * 8;
                Af[mt] = *reinterpret_cast<const short8*>(&xb[row * KPAD + k]);
            }
#pragma unroll
            for (int mt = 0; mt < 2; ++mt)
#pragma unroll
                for (int nt = 0; nt < 3; ++nt)
                    acc[mt][nt] = __builtin_amdgcn_mfma_f32_16x16x32_bf16(
                        Af[mt], Bf[nt][kk], acc[mt][nt], 0, 0, 0);
        }

        // C -> LDS (col = lane&15, row = (lane>>4)*4 + reg; m89-verified).
#pragma unroll
        for (int mt = 0; mt < 2; ++mt)
#pragma unroll
            for (int nt = 0; nt < 3; ++nt)
#pragma unroll
                for (int j = 0; j < 4; ++j) {
                    const int row = mt * 16 + q * 4 + j;
                    const int col = n0 + nt * 16 + cl;
                    cbuf[row * CST + col] = acc[mt][nt][j];
                }

        ds_barrier();   // barrier B: cbuf(t) ready; xb free for next stage.
    }

    // Final gather.
    if (thr < 96) {
        const int t = tend - 1;
        const int r = thr / 3, j = thr - r * 3;
        const int c = cid[(size_t)t * ROWS + r];
        out[((size_t)t * ROWS + r) * 3 + j] = cbuf[r * CST + 3 * c + j];
    }
}

// ---------- fallback (R2-style, fp32 weights, no workspace) ----------
template <int CTRL>
__device__ __forceinline__ float dpp_add_step(float x) {
    int s = __builtin_amdgcn_update_dpp(0, __float_as_int(x), CTRL,
                                        0xF, 0xF, true);
    return x + __int_as_float(s);
}
__device__ __forceinline__ float wave_reduce_sum(float x) {
    x = dpp_add_step<0x111>(x);
    x = dpp_add_step<0x112>(x);
    x = dpp_add_step<0x114>(x);
    x = dpp_add_step<0x118>(x);
    x = dpp_add_step<0x142>(x);
    x = dpp_add_step<0x143>(x);
    return x;   // lane 63
}

__global__ __launch_bounds__(256) void lad_fallback(
    const float* __restrict__ X, const int* __restrict__ cid,
    const float* __restrict__ Wp, const float* __restrict__ Wf,
    float* __restrict__ out, int n)
{
    const int lane = threadIdx.x & 63;
    const int wave = (int)((blockIdx.x * blockDim.x + threadIdx.x) >> 6);
    if (wave >= n) return;
    const size_t row = (size_t)wave;
    const float* xrow = X + row * (size_t)DIM;
    const float* xf   = xrow + POS;
    const int c3 = cid[row] * 3;
    const float* wp0 = Wp + (size_t)c3 * POS;
    const float* wf0 = Wf + (size_t)c3 * LAT;
    float a0 = 0.f, a1 = 0.f, a2 = 0.f;
#pragma unroll
    for (int i = 0; i < 4; ++i) {
        const int k = lane + 64 * i;
        const float x = xf[k];
        a0 = fmaf(x, wf0[k], a0);
        a1 = fmaf(x, wf0[k + LAT], a1);
        a2 = fmaf(x, wf0[k + 2 * LAT], a2);
    }
    if (lane < POS) {
        const float x = xrow[lane];
        a0 = fmaf(x, wp0[lane], a0);
        a1 = fmaf(x, wp0[lane + POS], a1);
        a2 = fmaf(x, wp0[lane + 2 * POS], a2);
    }
    a0 = wave_reduce_sum(a0);
    a1 = wave_reduce_sum(a1);
    a2 = wave_reduce_sum(a2);
    if (lane == 63) {
        float* o = out + row * 3;
        o[0] = a0; o[1] = a1; o[2] = a2;
    }
}

extern "C" void kernel_launch(void* const* d_in, const int* in_sizes, int n_in,
                              void* d_out, int out_size, void* d_ws, size_t ws_size,
                              hipStream_t stream) {
    const float* X   = (const float*)d_in[0];
    const int*   cid = (const int*)d_in[1];
    const float* Wp  = (const float*)d_in[2];
    const float* Wf  = (const float*)d_in[3];
    float* out = (float*)d_out;
    const int n = in_sizes[1];

    if (ws_size >= PW_BYTES && n > 0 && (n % ROWS) == 0) {
        unsigned* pw = (unsigned*)d_ws;
        pack_weights<<<(PW_DW + 255) / 256, 256, 0, stream>>>(Wp, Wf, pw);
        const int ntiles = n / ROWS;                       // 16384
        const int grid = (ntiles + TPB - 1) / TPB;         // 4096
        const long nf4 = (long)n * DIM / 4;
        lad_mfma<<<grid, 256, 0, stream>>>((const float4*)X, cid, pw, out,
                                           ntiles, nf4);
    } else {
        const int blocks = (n + 3) / 4;
        lad_fallback<<<blocks, 256, 0, stream>>>(X, cid, Wp, Wf, out, n);
    }
}

// Round 19
// 153.896 us; speedup vs baseline: 1.0772x; 1.0772x over previous
//
#include <hip/hip_runtime.h>

// LinearAutoDecoder R19: direct-to-LDS fp32 X (no reg staging), bf16 convert
// fused into A-fragment assembly (v_cvt_pk_bf16_f32), cbuf-free sparse output,
// double-buffered X slabs, 2 blocks/CU.
// R18 post-mortem: issue-rate-limited (6.6 B/cyc/CU issued = 4.1 TB/s); the
// reg-staging block (40x f2bf+ds_write_b16/thread) serialized delivery->use.
// This removes it: global_load_lds streams the 40,832B slab with probe-
// identical addresses; syncthreads' vmcnt drain IS the pipeline wait; slab
// t+1 delivers under MFMA(t); 2 anti-phased blocks keep HBM saturated.
// LDS: 2 x 40,832 = 81,664 B/block -> exactly 2 blocks/CU (163,328<=163,840).
// Fragment maps are the R17-proven ones (passed, absmax 0.03125).

constexpr int POS = 63, LAT = 256, DIM = 319, NCH = 192;
constexpr int ROWS = 32;                     // rows per tile
constexpr int PW_DW = NCH * 160;             // 30720 dwords (320 bf16/ch)
constexpr size_t PW_BYTES = (size_t)PW_DW * 4;
constexpr int TILE_DW = ROWS * DIM;          // 10208 dwords
constexpr int TILE_F4 = TILE_DW / 4;         // 2552 float4 per slab
constexpr int TPB = 16;                      // tiles per block

typedef __attribute__((ext_vector_type(8))) short short8;
typedef __attribute__((ext_vector_type(4))) float f32x4;

__device__ __forceinline__ unsigned f2bf(float f) {
    unsigned u = __float_as_uint(f);
    return (u + 0x7fffu + ((u >> 16) & 1u)) >> 16;
}

// pw[ch*160 + d] = bf16(w[ch][2d]) | bf16(w[ch][2d+1])<<16 ; k=319 -> 0
__global__ __launch_bounds__(256) void pack_weights(
    const float* __restrict__ Wp, const float* __restrict__ Wf,
    unsigned* __restrict__ pw)
{
    const int idx = blockIdx.x * 256 + threadIdx.x;
    if (idx >= PW_DW) return;
    const int ch = idx / 160, d = idx - ch * 160;
    auto wat = [&](int k) -> float {
        if (k < POS) return Wp[ch * POS + k];
        if (k < DIM) return Wf[ch * LAT + (k - POS)];
        return 0.f;
    };
    pw[idx] = f2bf(wat(2 * d)) | (f2bf(wat(2 * d + 1)) << 16);
}

__global__ __launch_bounds__(256, 2) void lad_mfma2(
    const float4* __restrict__ X4, const int* __restrict__ cid,
    const unsigned* __restrict__ pw, float* __restrict__ out,
    int ntiles)
{
    __shared__ float xb[2][TILE_DW];   // 81,664 B (double-buffered slab)

    const int thr = threadIdx.x;
    const int l   = thr & 63;
    const int wid = thr >> 6;
    const int n0  = wid * 48;          // wave's channel base
    const int cl  = l & 15;            // row(A) / col(B,C)
    const int q   = l >> 4;            // k-quad

    // B fragments: 48 channels x K=320 in VGPRs (R17-proven load).
    short8 Bf[3][10];
#pragma unroll
    for (int nt = 0; nt < 3; ++nt)
#pragma unroll
        for (int kk = 0; kk < 10; ++kk)
            Bf[nt][kk] = *reinterpret_cast<const short8*>(
                pw + (size_t)(n0 + nt * 16 + cl) * 160 + kk * 16 + q * 4);

    const int t0 = blockIdx.x * TPB;
    const int tend = min(t0 + TPB, ntiles);
    if (t0 >= tend) return;

    // Direct-to-LDS slab stage: lane-contiguous dwordx4 (probe pattern).
    auto stage = [&](int tile, int p) {
        const float4* src = X4 + (size_t)tile * TILE_F4;
#pragma unroll
        for (int j = 0; j < 10; ++j) {
            const int slot = j * 256 + thr;
            if (slot < TILE_F4)
                __builtin_amdgcn_global_load_lds(
                    (const __attribute__((address_space(1))) unsigned int*)(src + slot),
                    (__attribute__((address_space(3))) unsigned int*)&xb[p][slot * 4],
                    16, 0, 0);
        }
    };

    stage(t0, 0);
    __syncthreads();                   // prologue drain

    int p = 0;
    for (int t = t0; t < tend; ++t) {
        // Fire next slab into the other buffer: delivers under MFMA below.
        if (t + 1 < tend) stage(t + 1, p ^ 1);

        // cid for this lane's 8 output rows (L1-hot, overlaps MFMA).
        int c3v[2][4];
#pragma unroll
        for (int mt = 0; mt < 2; ++mt)
#pragma unroll
            for (int j = 0; j < 4; ++j)
                c3v[mt][j] = 3 * cid[(size_t)t * ROWS + mt * 16 + q * 4 + j];

        f32x4 acc[2][3];
#pragma unroll
        for (int mt = 0; mt < 2; ++mt)
#pragma unroll
            for (int nt = 0; nt < 3; ++nt)
                acc[mt][nt] = (f32x4)0.0f;

        // MFMA over K=320: A-frags read fp32 from LDS, cvt_pk to bf16 in-reg.
#pragma unroll
        for (int kk = 0; kk < 10; ++kk) {
            short8 Af[2];
#pragma unroll
            for (int mt = 0; mt < 2; ++mt) {
                const float* fp = &xb[p][(mt * 16 + cl) * DIM + kk * 32 + q * 8];
                union { unsigned u[4]; short8 s; } cv;
#pragma unroll
                for (int h = 0; h < 4; ++h) {
                    asm("v_cvt_pk_bf16_f32 %0, %1, %2"
                        : "=v"(cv.u[h]) : "v"(fp[2 * h]), "v"(fp[2 * h + 1]));
                }
                Af[mt] = cv.s;
            }
#pragma unroll
            for (int mt = 0; mt < 2; ++mt)
#pragma unroll
                for (int nt = 0; nt < 3; ++nt)
                    acc[mt][nt] = __builtin_amdgcn_mfma_f32_16x16x32_bf16(
                        Af[mt], Bf[nt][kk], acc[mt][nt], 0, 0, 0);
        }

        // Sparse direct output: each lane stores its acc elements whose col
        // hits the row's 3 selected channels (mapping R17-proven).
#pragma unroll
        for (int mt = 0; mt < 2; ++mt)
#pragma unroll
            for (int j = 0; j < 4; ++j) {
                const int grow = t * ROWS + mt * 16 + q * 4 + j;
                const int c3 = c3v[mt][j];
#pragma unroll
                for (int nt = 0; nt < 3; ++nt) {
                    const int col = n0 + nt * 16 + cl;
                    const unsigned d = (unsigned)(col - c3);
                    if (d < 3u)
                        out[(size_t)grow * 3 + d] = acc[mt][nt][j];
                }
            }

        __syncthreads();   // drains slab(t+1) + stores; buffers swap safely
        p ^= 1;
    }
}

// ---------- fallback (R2-style, fp32 weights, no workspace) ----------
template <int CTRL>
__device__ __forceinline__ float dpp_add_step(float x) {
    int s = __builtin_amdgcn_update_dpp(0, __float_as_int(x), CTRL,
                                        0xF, 0xF, true);
    return x + __int_as_float(s);
}
__device__ __forceinline__ float wave_reduce_sum(float x) {
    x = dpp_add_step<0x111>(x);
    x = dpp_add_step<0x112>(x);
    x = dpp_add_step<0x114>(x);
    x = dpp_add_step<0x118>(x);
    x = dpp_add_step<0x142>(x);
    x = dpp_add_step<0x143>(x);
    return x;   // lane 63
}

__global__ __launch_bounds__(256) void lad_fallback(
    const float* __restrict__ X, const int* __restrict__ cid,
    const float* __restrict__ Wp, const float* __restrict__ Wf,
    float* __restrict__ out, int n)
{
    const int lane = threadIdx.x & 63;
    const int wave = (int)((blockIdx.x * blockDim.x + threadIdx.x) >> 6);
    if (wave >= n) return;
    const size_t row = (size_t)wave;
    const float* xrow = X + row * (size_t)DIM;
    const float* xf   = xrow + POS;
    const int c3 = cid[row] * 3;
    const float* wp0 = Wp + (size_t)c3 * POS;
    const float* wf0 = Wf + (size_t)c3 * LAT;
    float a0 = 0.f, a1 = 0.f, a2 = 0.f;
#pragma unroll
    for (int i = 0; i < 4; ++i) {
        const int k = lane + 64 * i;
        const float x = xf[k];
        a0 = fmaf(x, wf0[k], a0);
        a1 = fmaf(x, wf0[k + LAT], a1);
        a2 = fmaf(x, wf0[k + 2 * LAT], a2);
    }
    if (lane < POS) {
        const float x = xrow[lane];
        a0 = fmaf(x, wp0[lane], a0);
        a1 = fmaf(x, wp0[lane + POS], a1);
        a2 = fmaf(x, wp0[lane + 2 * POS], a2);
    }
    a0 = wave_reduce_sum(a0);
    a1 = wave_reduce_sum(a1);
    a2 = wave_reduce_sum(a2);
    if (lane == 63) {
        float* o = out + row * 3;
        o[0] = a0; o[1] = a1; o[2] = a2;
    }
}

extern "C" void kernel_launch(void* const* d_in, const int* in_sizes, int n_in,
                              void* d_out, int out_size, void* d_ws, size_t ws_size,
                              hipStream_t stream) {
    const float* X   = (const float*)d_in[0];
    const int*   cid = (const int*)d_in[1];
    const float* Wp  = (const float*)d_in[2];
    const float* Wf  = (const float*)d_in[3];
    float* out = (float*)d_out;
    const int n = in_sizes[1];

    if (ws_size >= PW_BYTES && n > 0 && (n % ROWS) == 0) {
        unsigned* pw = (unsigned*)d_ws;
        pack_weights<<<(PW_DW + 255) / 256, 256, 0, stream>>>(Wp, Wf, pw);
        const int ntiles = n / ROWS;                       // 16384
        const int grid = (ntiles + TPB - 1) / TPB;         // 1024
        lad_mfma2<<<grid, 256, 0, stream>>>((const float4*)X, cid, pw, out,
                                            ntiles);
    } else {
        const int blocks = (n + 3) / 4;
        lad_fallback<<<blocks, 256, 0, stream>>>(X, cid, Wp, Wf, out, n);
    }
}

// Round 20
// 146.490 us; speedup vs baseline: 1.1317x; 1.0506x over previous
//
#include <hip/hip_runtime.h>

// LinearAutoDecoder R20: R19 (direct-to-LDS X, fused cvt_pk, sparse output)
// with 50% more concurrency: ROWS 32->16 (slab 20,416B, dbuf 40,832B/block)
// + launch_bounds(256,3) -> 3 blocks/CU = 12 waves (3/SIMD vs R19's 2/SIMD).
// R19 post-mortem: compute phase is a DS-latency chain (80 ds_read_b64 +
// cvt_pk per wave) at 2 waves/SIMD -- latency unhidden, compute ~3.5k cyc >
// HBM share. Halving the tile halves per-wave DS work (40 b64) and drops
// VGPR need (mt=1: Bf 120 + acc 12 + misc ~ 155 < 170 cap, no spill);
// 3 anti-phased blocks make HBM demand continuous.

constexpr int POS = 63, LAT = 256, DIM = 319, NCH = 192;
constexpr int ROWS = 16;                     // rows per tile
constexpr int PW_DW = NCH * 160;             // 30720 dwords (320 bf16/ch)
constexpr size_t PW_BYTES = (size_t)PW_DW * 4;
constexpr int TILE_DW = ROWS * DIM;          // 5104 dwords
constexpr int TILE_F4 = TILE_DW / 4;         // 1276 float4 per slab
constexpr int GRID = 768;                    // 3 blocks/CU, all resident

typedef __attribute__((ext_vector_type(8))) short short8;
typedef __attribute__((ext_vector_type(4))) float f32x4;

__device__ __forceinline__ unsigned f2bf(float f) {
    unsigned u = __float_as_uint(f);
    return (u + 0x7fffu + ((u >> 16) & 1u)) >> 16;
}

// pw[ch*160 + d] = bf16(w[ch][2d]) | bf16(w[ch][2d+1])<<16 ; k=319 -> 0
__global__ __launch_bounds__(256) void pack_weights(
    const float* __restrict__ Wp, const float* __restrict__ Wf,
    unsigned* __restrict__ pw)
{
    const int idx = blockIdx.x * 256 + threadIdx.x;
    if (idx >= PW_DW) return;
    const int ch = idx / 160, d = idx - ch * 160;
    auto wat = [&](int k) -> float {
        if (k < POS) return Wp[ch * POS + k];
        if (k < DIM) return Wf[ch * LAT + (k - POS)];
        return 0.f;
    };
    pw[idx] = f2bf(wat(2 * d)) | (f2bf(wat(2 * d + 1)) << 16);
}

__global__ __launch_bounds__(256, 3) void lad_mfma3(
    const float4* __restrict__ X4, const int* __restrict__ cid,
    const unsigned* __restrict__ pw, float* __restrict__ out,
    int ntiles, int tpb)
{
    __shared__ float xb[2][TILE_DW];   // 40,832 B -> 3 blocks/CU

    const int thr = threadIdx.x;
    const int l   = thr & 63;
    const int wid = thr >> 6;
    const int n0  = wid * 48;          // wave's channel base
    const int cl  = l & 15;            // row(A) / col(B,C)
    const int q   = l >> 4;            // k-quad

    // B fragments: 48 channels x K=320 in VGPRs (R17-proven load).
    short8 Bf[3][10];
#pragma unroll
    for (int nt = 0; nt < 3; ++nt)
#pragma unroll
        for (int kk = 0; kk < 10; ++kk)
            Bf[nt][kk] = *reinterpret_cast<const short8*>(
                pw + (size_t)(n0 + nt * 16 + cl) * 160 + kk * 16 + q * 4);

    const int t0 = blockIdx.x * tpb;
    const int tend = min(t0 + tpb, ntiles);
    if (t0 >= tend) return;

    // Direct-to-LDS slab stage: lane-contiguous dwordx4 (probe pattern).
    auto stage = [&](int tile, int p) {
        const float4* src = X4 + (size_t)tile * TILE_F4;
#pragma unroll
        for (int j = 0; j < 5; ++j) {
            const int slot = j * 256 + thr;
            if (slot < TILE_F4)
                __builtin_amdgcn_global_load_lds(
                    (const __attribute__((address_space(1))) unsigned int*)(src + slot),
                    (__attribute__((address_space(3))) unsigned int*)&xb[p][slot * 4],
                    16, 0, 0);
        }
    };

    stage(t0, 0);
    __syncthreads();                   // prologue drain

    int p = 0;
    for (int t = t0; t < tend; ++t) {
        // Fire next slab into the other buffer: delivers under MFMA below.
        if (t + 1 < tend) stage(t + 1, p ^ 1);

        // cid for this lane's 4 output rows (L1-hot, overlaps MFMA).
        int c3v[4];
#pragma unroll
        for (int j = 0; j < 4; ++j)
            c3v[j] = 3 * cid[(size_t)t * ROWS + q * 4 + j];

        f32x4 acc[3];
#pragma unroll
        for (int nt = 0; nt < 3; ++nt)
            acc[nt] = (f32x4)0.0f;

        // MFMA over K=320: A-frag reads fp32 from LDS, cvt_pk to bf16 in-reg.
#pragma unroll
        for (int kk = 0; kk < 10; ++kk) {
            const float* fp = &xb[p][cl * DIM + kk * 32 + q * 8];
            union { unsigned u[4]; short8 s; } cv;
#pragma unroll
            for (int h = 0; h < 4; ++h) {
                asm("v_cvt_pk_bf16_f32 %0, %1, %2"
                    : "=v"(cv.u[h]) : "v"(fp[2 * h]), "v"(fp[2 * h + 1]));
            }
#pragma unroll
            for (int nt = 0; nt < 3; ++nt)
                acc[nt] = __builtin_amdgcn_mfma_f32_16x16x32_bf16(
                    cv.s, Bf[nt][kk], acc[nt], 0, 0, 0);
        }

        // Sparse direct output: lane stores acc elements whose col hits the
        // row's 3 selected channels (mapping R17/R19-proven).
#pragma unroll
        for (int j = 0; j < 4; ++j) {
            const int grow = t * ROWS + q * 4 + j;
            const int c3 = c3v[j];
#pragma unroll
            for (int nt = 0; nt < 3; ++nt) {
                const int col = n0 + nt * 16 + cl;
                const unsigned d = (unsigned)(col - c3);
                if (d < 3u)
                    out[(size_t)grow * 3 + d] = acc[nt][j];
            }
        }

        __syncthreads();   // drains slab(t+1) + stores; buffers swap safely
        p ^= 1;
    }
}

// ---------- fallback (R2-style, fp32 weights, no workspace) ----------
template <int CTRL>
__device__ __forceinline__ float dpp_add_step(float x) {
    int s = __builtin_amdgcn_update_dpp(0, __float_as_int(x), CTRL,
                                        0xF, 0xF, true);
    return x + __int_as_float(s);
}
__device__ __forceinline__ float wave_reduce_sum(float x) {
    x = dpp_add_step<0x111>(x);
    x = dpp_add_step<0x112>(x);
    x = dpp_add_step<0x114>(x);
    x = dpp_add_step<0x118>(x);
    x = dpp_add_step<0x142>(x);
    x = dpp_add_step<0x143>(x);
    return x;   // lane 63
}

__global__ __launch_bounds__(256) void lad_fallback(
    const float* __restrict__ X, const int* __restrict__ cid,
    const float* __restrict__ Wp, const float* __restrict__ Wf,
    float* __restrict__ out, int n)
{
    const int lane = threadIdx.x & 63;
    const int wave = (int)((blockIdx.x * blockDim.x + threadIdx.x) >> 6);
    if (wave >= n) return;
    const size_t row = (size_t)wave;
    const float* xrow = X + row * (size_t)DIM;
    const float* xf   = xrow + POS;
    const int c3 = cid[row] * 3;
    const float* wp0 = Wp + (size_t)c3 * POS;
    const float* wf0 = Wf + (size_t)c3 * LAT;
    float a0 = 0.f, a1 = 0.f, a2 = 0.f;
#pragma unroll
    for (int i = 0; i < 4; ++i) {
        const int k = lane + 64 * i;
        const float x = xf[k];
        a0 = fmaf(x, wf0[k], a0);
        a1 = fmaf(x, wf0[k + LAT], a1);
        a2 = fmaf(x, wf0[k + 2 * LAT], a2);
    }
    if (lane < POS) {
        const float x = xrow[lane];
        a0 = fmaf(x, wp0[lane], a0);
        a1 = fmaf(x, wp0[lane + POS], a1);
        a2 = fmaf(x, wp0[lane + 2 * POS], a2);
    }
    a0 = wave_reduce_sum(a0);
    a1 = wave_reduce_sum(a1);
    a2 = wave_reduce_sum(a2);
    if (lane == 63) {
        float* o = out + row * 3;
        o[0] = a0; o[1] = a1; o[2] = a2;
    }
}

extern "C" void kernel_launch(void* const* d_in, const int* in_sizes, int n_in,
                              void* d_out, int out_size, void* d_ws, size_t ws_size,
                              hipStream_t stream) {
    const float* X   = (const float*)d_in[0];
    const int*   cid = (const int*)d_in[1];
    const float* Wp  = (const float*)d_in[2];
    const float* Wf  = (const float*)d_in[3];
    float* out = (float*)d_out;
    const int n = in_sizes[1];

    if (ws_size >= PW_BYTES && n > 0 && (n % ROWS) == 0) {
        unsigned* pw = (unsigned*)d_ws;
        pack_weights<<<(PW_DW + 255) / 256, 256, 0, stream>>>(Wp, Wf, pw);
        const int ntiles = n / ROWS;                       // 32768
        const int tpb = (ntiles + GRID - 1) / GRID;        // 43
        lad_mfma3<<<GRID, 256, 0, stream>>>((const float4*)X, cid, pw, out,
                                            ntiles, tpb);
    } else {
        const int blocks = (n + 3) / 4;
        lad_fallback<<<blocks, 256, 0, stream>>>(X, cid, Wp, Wf, out, n);
    }
}